// Round 6
// baseline (1610.480 us; speedup 1.0000x reference)
//
#include <hip/hip_runtime.h>
#include <math.h>

typedef __attribute__((ext_vector_type(4))) float f32x4;
typedef __attribute__((ext_vector_type(2))) float f32x2;
typedef __attribute__((ext_vector_type(8))) short bf16x8;
typedef __attribute__((ext_vector_type(4))) short short4v;

#define EPSN 1e-12f
#define TN 16
#define NBLK 1024

__device__ inline short f2bf(float x) {
    union { float f; unsigned u; } v; v.f = x;
    unsigned r = v.u + 0x7fffu + ((v.u >> 16) & 1u);
    return (short)(r >> 16);
}
__device__ inline float bf2f(short s) {
    union { unsigned u; float f; } v;
    v.u = ((unsigned)(unsigned short)s) << 16;
    return v.f;
}
__device__ inline float wsum64(float v) {
#pragma unroll
    for (int m = 32; m > 0; m >>= 1) v += __shfl_xor(v, m);
    return v;
}
__device__ inline float wsum32(float v) {
    v += __shfl_xor(v, 1);
    v += __shfl_xor(v, 2);
    v += __shfl_xor(v, 4);
    v += __shfl_xor(v, 8);
    v += __shfl_xor(v, 16);
    return v;
}
__device__ inline float sigm(float x) { return 1.0f / (1.0f + __expf(-x)); }
__device__ inline float tanh_fast(float x) {
    float a = fabsf(x);
    float e = __expf(2.0f * a);
    float t = 1.0f - 2.0f / (e + 1.0f);
    return copysignf(t, x);
}
__device__ inline float dot4(f32x4 v) { return v.x*v.x + v.y*v.y + v.z*v.z + v.w*v.w; }

// ---- prep: W_f (256x256) + W_iou (384x256) -> bf16 fragment-linear B ----
__global__ void prep_B(const float* __restrict__ W_f, const float* __restrict__ W_iou,
                       short* __restrict__ Blin) {
    int t = blockIdx.x * 256 + threadIdx.x;
    if (t >= 8 * 40 * 64) return;
    int lane = t & 63;
    int jb = (t >> 6) % 40;
    int kb = (t >> 6) / 40;
    int j = jb * 16 + (lane & 15);
    int k = kb * 32 + ((lane >> 4) << 3);
    const float* src = (j < 256) ? (W_f + (size_t)j * 256 + k)
                                 : (W_iou + (size_t)(j - 256) * 256 + k);
    bf16x8 v;
#pragma unroll
    for (int e = 0; e < 8; ++e) v[e] = f2bf(src[e]);
    *(bf16x8*)(Blin + (size_t)t * 8) = v;
}

// ---- fused, persistent, cross-tile pipelined ----
// LDS map (shorts): A0 [0,4096)  A1 [4096,8192)  F [8192,12288)  IOU [12288,18432)
__global__ __launch_bounds__(512, 8) void tree_fused(
    const float* __restrict__ h_src, const float* __restrict__ c_src,
    const float* __restrict__ iou, const int* __restrict__ child_idx,
    const float* __restrict__ b_f, const float* __restrict__ b_iou,
    const float* __restrict__ sc_iou_p, const float* __restrict__ sc_c_p,
    const short* __restrict__ Blin, float* __restrict__ out, int ntiles) {
    __shared__ __align__(16) short U[18432];
    __shared__ float h_n2[2][TN], iou_n2[2][TN];
    __shared__ int cc_lds[2][TN][2];

    const int tid = threadIdx.x;
    const int wave = tid >> 6;
    const int lane = tid & 63;
    const int G = gridDim.x;

    const float sc_iou = sc_iou_p[0];
    const float sc_c = sc_c_p[0];

    const int child = lane >> 5;
    const int seg = lane & 31;
    const int arow = lane & 15;
    const int kgrp = lane >> 4;

    // hoisted b_f accumulator-init values (constant per thread)
    const float bf0 = b_f[(wave * 2 + 0) * 16 + arow];
    const float bf1 = b_f[(wave * 2 + 1) * 16 + arow];

    const int t0 = blockIdx.x;
    if (t0 >= ntiles) return;

    int idxA[2];
    // ---------- prologue: stage tile t0, prefetch idx(t0+G) ----------
    {
#pragma unroll
        for (int r = 0; r < 2; ++r)
            idxA[r] = child_idx[(size_t)(t0 * TN + wave + 8 * r) * 2 + child];
        f32x4 hv[2];
#pragma unroll
        for (int r = 0; r < 2; ++r)
            hv[r] = *(const f32x4*)(h_src + (size_t)idxA[r] * 128 + seg * 4);
        f32x4 iv4[2]; f32x2 iv2[2];
#pragma unroll
        for (int r = 0; r < 2; ++r) {
            const size_t nb = (size_t)(t0 * TN + wave + 8 * r) * 384;
            iv4[r] = *(const f32x4*)(iou + nb + lane * 4);
            iv2[r] = *(const f32x2*)(iou + nb + 256 + lane * 2);
        }
#pragma unroll
        for (int r = 0; r < 2; ++r) {
            const int nd = wave + 8 * r;
            short4v a4;
            a4.x = f2bf(hv[r].x); a4.y = f2bf(hv[r].y);
            a4.z = f2bf(hv[r].z); a4.w = f2bf(hv[r].w);
            *(short4v*)((char*)U + nd * 512 + ((lane * 8) ^ (wave << 4))) = a4;
            if (lane == 0) cc_lds[0][nd][0] = idxA[r];
            if (lane == 32) cc_lds[0][nd][1] = idxA[r];
            float hss = dot4(hv[r]);
            float iss = dot4(iv4[r]) + iv2[r].x * iv2[r].x + iv2[r].y * iv2[r].y;
            hss = wsum64(hss);
            iss = wsum64(iss);
            if (lane == 0) { h_n2[0][nd] = hss; iou_n2[0][nd] = iss; }
        }
        if (t0 + G < ntiles) {
#pragma unroll
            for (int r = 0; r < 2; ++r)
                idxA[r] = child_idx[(size_t)((t0 + G) * TN + wave + 8 * r) * 2 + child];
        }
    }
    __syncthreads();

    int b = 0;
    for (int t = t0; t < ntiles; t += G, b ^= 1) {
        const int nt = t + G;
        const bool hn = nt < ntiles;
        const int Ab = b * 8192;          // byte offset of A[b]
        const int An = 8192 - Ab;         // byte offset of A[b^1]

        // ---- issue next-tile h gathers (fly during GEMM) ----
        f32x4 hvn[2];
        if (hn) {
#pragma unroll
            for (int r = 0; r < 2; ++r)
                hvn[r] = *(const f32x4*)(h_src + (size_t)idxA[r] * 128 + seg * 4);
        }

        // ---- GEMM-F: cols 0..255, b_f folded ----
        f32x4 accf[2];
        accf[0] = (f32x4){bf0, bf0, bf0, bf0};
        accf[1] = (f32x4){bf1, bf1, bf1, bf1};
#pragma unroll
        for (int kb = 0; kb < 8; ++kb) {
            const bf16x8 af = *(const bf16x8*)((const char*)U + Ab + arow * 512 +
                                ((kb * 64 + kgrp * 16) ^ ((arow & 7) << 4)));
#pragma unroll
            for (int jj = 0; jj < 2; ++jj) {
                const int jbg = wave * 2 + jj;
                const bf16x8 bfr = *(const bf16x8*)(Blin + ((size_t)(kb * 40 + jbg) * 64 + lane) * 8);
                accf[jj] = __builtin_amdgcn_mfma_f32_16x16x32_bf16(af, bfr, accf[jj], 0, 0, 0);
            }
        }
        // F spill
#pragma unroll
        for (int jj = 0; jj < 2; ++jj) {
            const int col = (wave * 2 + jj) * 16 + arow;
#pragma unroll
            for (int r = 0; r < 4; ++r) {
                const int row = kgrp * 4 + r;
                U[8192 + row * 256 + (col ^ (((row >> 2) & 3) << 4))] = f2bf(accf[jj][r]);
            }
        }

        // ---- GEMM-IOU: cols 256..639 ----
        f32x4 accio[3];
#pragma unroll
        for (int jj = 0; jj < 3; ++jj) accio[jj] = (f32x4){0.f, 0.f, 0.f, 0.f};
#pragma unroll
        for (int kb = 0; kb < 8; ++kb) {
            const bf16x8 af = *(const bf16x8*)((const char*)U + Ab + arow * 512 +
                                ((kb * 64 + kgrp * 16) ^ ((arow & 7) << 4)));
#pragma unroll
            for (int jj = 0; jj < 3; ++jj) {
                const int jbg = 16 + wave * 3 + jj;
                const bf16x8 bfr = *(const bf16x8*)(Blin + ((size_t)(kb * 40 + jbg) * 64 + lane) * 8);
                accio[jj] = __builtin_amdgcn_mfma_f32_16x16x32_bf16(af, bfr, accio[jj], 0, 0, 0);
            }
        }
        __syncthreads();   // B1: F visible; prev part2 IOU-reads drained

        // ---- part1: epilogue-1 of t  ||  staging of t+1 ----
        float csr[4], s_iou_v;
        {
            const int nd = tid >> 5;
            const int q = tid & 31;
            const int h0 = q * 4;

            const int c0i = cc_lds[b][nd][0];
            const int c1i = cc_lds[b][nd][1];
            const f32x4 c0v = *(const f32x4*)(c_src + (size_t)c0i * 128 + h0);
            const f32x4 c1v = *(const f32x4*)(c_src + (size_t)c1i * 128 + h0);

            f32x4 iv4[2]; f32x2 iv2[2];
            if (hn) {
#pragma unroll
                for (int r = 0; r < 2; ++r) {
                    const size_t nb = (size_t)(nt * TN + wave + 8 * r) * 384;
                    iv4[r] = *(const f32x4*)(iou + nb + lane * 4);
                    iv2[r] = *(const f32x2*)(iou + nb + 256 + lane * 2);
                }
            }
            // forget-gate reads (LDS, overlap with VMEM waits)
            const int fsw = ((nd >> 2) & 3) << 4;
            const short4v yf0 = *(const short4v*)&U[8192 + nd * 256 + (h0 ^ fsw)];
            const short4v yf1 = *(const short4v*)&U[8192 + nd * 256 + ((128 + h0) ^ fsw)];

            if (hn) {
#pragma unroll
                for (int r = 0; r < 2; ++r) {
                    const int nd2 = wave + 8 * r;
                    short4v a4;
                    a4.x = f2bf(hvn[r].x); a4.y = f2bf(hvn[r].y);
                    a4.z = f2bf(hvn[r].z); a4.w = f2bf(hvn[r].w);
                    *(short4v*)((char*)U + An + nd2 * 512 + ((lane * 8) ^ (wave << 4))) = a4;
                    if (lane == 0) cc_lds[b ^ 1][nd2][0] = idxA[r];
                    if (lane == 32) cc_lds[b ^ 1][nd2][1] = idxA[r];
                    float hss = dot4(hvn[r]);
                    float iss = dot4(iv4[r]) + iv2[r].x * iv2[r].x + iv2[r].y * iv2[r].y;
                    hss = wsum64(hss);
                    iss = wsum64(iss);
                    if (lane == 0) { h_n2[b ^ 1][nd2] = hss; iou_n2[b ^ 1][nd2] = iss; }
                }
            }
            if (nt + G < ntiles) {
#pragma unroll
                for (int r = 0; r < 2; ++r)
                    idxA[r] = child_idx[(size_t)((nt + G) * TN + wave + 8 * r) * 2 + child];
            }

            float c0n2 = dot4(c0v);
            c0n2 = wsum32(c0n2);
            float cs[4];
            float csn2 = 0.f;
#pragma unroll
            for (int e = 0; e < 4; ++e) {
                const float f0 = sigm(bf2f(yf0[e]));   // b_f folded into Y
                const float f1 = sigm(bf2f(yf1[e]));
                const float v = f0 * ((const float*)&c0v)[e] + f1 * ((const float*)&c1v)[e];
                cs[e] = v;
                csn2 += v * v;
            }
            csn2 = wsum32(csn2);
            const float rs = sc_c * sqrtf(c0n2) / fmaxf(sqrtf(csn2), EPSN);
#pragma unroll
            for (int e = 0; e < 4; ++e) csr[e] = cs[e] * rs;
            s_iou_v = sc_iou * sqrtf(iou_n2[b][nd]) / fmaxf(sqrtf(h_n2[b][nd]), EPSN);
        }
        __syncthreads();   // B2: part1 F-reads + A[b^1] writes complete

        // ---- IOU spill ----
#pragma unroll
        for (int jj = 0; jj < 3; ++jj) {
            const int col = (wave * 3 + jj) * 16 + arow;
#pragma unroll
            for (int r = 0; r < 4; ++r) {
                const int row = kgrp * 4 + r;
                U[12288 + row * 384 + (col ^ (((row >> 2) & 3) << 4))] = f2bf(accio[jj][r]);
            }
        }
        __syncthreads();   // B3

        // ---- part2: i/o/u gates -> h, c ----
        {
            const int nd = tid >> 5;
            const int q = tid & 31;
            const int h0 = q * 4;
            const int iosw = ((nd >> 2) & 3) << 4;
            const short4v yi = *(const short4v*)&U[12288 + nd * 384 + (h0 ^ iosw)];
            const short4v yo = *(const short4v*)&U[12288 + nd * 384 + ((128 + h0) ^ iosw)];
            const short4v yu = *(const short4v*)&U[12288 + nd * 384 + ((256 + h0) ^ iosw)];
            const f32x4 bi0 = *(const f32x4*)(b_iou + h0);
            const f32x4 bi1 = *(const f32x4*)(b_iou + 128 + h0);
            const f32x4 bi2 = *(const f32x4*)(b_iou + 256 + h0);
            const size_t node = (size_t)t * TN + nd;
            f32x4 outh, outc;
#pragma unroll
            for (int e = 0; e < 4; ++e) {
                const float iv = bf2f(yi[e]) * s_iou_v + ((const float*)&bi0)[e];
                const float ov = bf2f(yo[e]) * s_iou_v + ((const float*)&bi1)[e];
                const float uv = bf2f(yu[e]) * s_iou_v + ((const float*)&bi2)[e];
                const float cval = sigm(iv) * tanh_fast(uv) + csr[e];
                const float hval = sigm(ov) * tanh_fast(cval);
                ((float*)&outh)[e] = hval;
                ((float*)&outc)[e] = cval;
            }
            *(f32x4*)(out + node * 256 + h0) = outh;
            *(f32x4*)(out + node * 256 + 128 + h0) = outc;
        }
    }
}

extern "C" void kernel_launch(void* const* d_in, const int* in_sizes, int n_in,
                              void* d_out, int out_size, void* d_ws, size_t ws_size,
                              hipStream_t stream) {
    const float* h_src = (const float*)d_in[0];
    const float* c_src = (const float*)d_in[1];
    const float* iou = (const float*)d_in[2];
    const int* cidx = (const int*)d_in[3];
    const float* W_f = (const float*)d_in[4];
    const float* b_f = (const float*)d_in[5];
    const float* W_iou = (const float*)d_in[6];
    const float* b_iou = (const float*)d_in[7];
    const float* s_iou = (const float*)d_in[8];
    const float* s_c = (const float*)d_in[9];
    float* out = (float*)d_out;
    short* Blin = (short*)d_ws;

    const int N = in_sizes[3] / 2;        // 200000
    const int ntiles = N / TN;            // 12500
    const int grid = (ntiles < NBLK) ? ntiles : NBLK;
    hipLaunchKernelGGL(prep_B, dim3(80), dim3(256), 0, stream, W_f, W_iou, Blin);
    hipLaunchKernelGGL(tree_fused, dim3(grid), dim3(512), 0, stream,
                       h_src, c_src, iou, cidx, b_f, b_iou, s_iou, s_c, Blin, out, ntiles);
}

// Round 7
// 750.300 us; speedup vs baseline: 2.1464x; 2.1464x over previous
//
#include <hip/hip_runtime.h>
#include <math.h>

typedef __attribute__((ext_vector_type(4))) float f32x4;
typedef __attribute__((ext_vector_type(2))) float f32x2;
typedef __attribute__((ext_vector_type(8))) short bf16x8;
typedef __attribute__((ext_vector_type(4))) short short4v;

#define EPSN 1e-12f

__device__ inline short f2bf(float x) {
    union { float f; unsigned u; } v; v.f = x;
    unsigned r = v.u + 0x7fffu + ((v.u >> 16) & 1u);
    return (short)(r >> 16);
}
__device__ inline float wsum64(float v) {
#pragma unroll
    for (int m = 32; m > 0; m >>= 1) v += __shfl_xor(v, m);
    return v;
}
__device__ inline float wsum16(float v) {
    v += __shfl_xor(v, 1);
    v += __shfl_xor(v, 2);
    v += __shfl_xor(v, 4);
    v += __shfl_xor(v, 8);
    return v;
}
__device__ inline float sigm(float x) { return 1.0f / (1.0f + __expf(-x)); }
__device__ inline float tanh_fast(float x) {
    float a = fabsf(x);
    float e = __expf(2.0f * a);
    float t = 1.0f - 2.0f / (e + 1.0f);
    return copysignf(t, x);
}
__device__ inline float dot4(f32x4 v) { return v.x*v.x + v.y*v.y + v.z*v.z + v.w*v.w; }

// ---- prep: W_f (256x256) + W_iou (384x256) -> bf16 fragment-linear B ----
__global__ void prep_B(const float* __restrict__ W_f, const float* __restrict__ W_iou,
                       short* __restrict__ Blin) {
    int t = blockIdx.x * 256 + threadIdx.x;
    if (t >= 8 * 40 * 64) return;
    int lane = t & 63;
    int jb = (t >> 6) % 40;
    int kb = (t >> 6) / 40;
    int j = jb * 16 + (lane & 15);
    int k = kb * 32 + ((lane >> 4) << 3);
    const float* src = (j < 256) ? (W_f + (size_t)j * 256 + k)
                                 : (W_iou + (size_t)(j - 256) * 256 + k);
    bf16x8 v;
#pragma unroll
    for (int e = 0; e < 8; ++e) v[e] = f2bf(src[e]);
    *(bf16x8*)(Blin + (size_t)t * 8) = v;
}

// GEMM pass over the wave-private A tile: NJJ output col-blocks starting at jbase.
template<int NJJ>
__device__ inline void gpass(const short* __restrict__ Aw, const short* __restrict__ Blin,
                             int lane, int rg, int jbase, f32x4* acc) {
#pragma unroll
    for (int kb = 0; kb < 8; ++kb) {
        const int slot = (kb << 6) + (rg << 4) + (lane & 15);
        const bf16x8 af = *(const bf16x8*)&Aw[(slot ^ ((slot >> 4) & 7)) << 3];
#pragma unroll
        for (int jj = 0; jj < NJJ; ++jj) {
            const bf16x8 bfr = *(const bf16x8*)(Blin +
                ((size_t)((kb * 40 + jbase + jj) * 64 + lane)) * 8);
            acc[jj] = __builtin_amdgcn_mfma_f32_16x16x32_bf16(af, bfr, acc[jj], 0, 0, 0);
        }
    }
}

// ---- fused, wave-autonomous: 16 nodes per wave, no __syncthreads ----
__global__ __launch_bounds__(256, 4) void tree_fused(
    const float* __restrict__ h_src, const float* __restrict__ c_src,
    const float* __restrict__ iou, const int* __restrict__ child_idx,
    const float* __restrict__ b_f, const float* __restrict__ b_iou,
    const float* __restrict__ sc_iou_p, const float* __restrict__ sc_c_p,
    const short* __restrict__ Blin, float* __restrict__ out) {
    __shared__ short A[4][4096];   // per-wave 8KB A tile, fragment-linear + XOR swizzle

    const int lane = threadIdx.x & 63;
    const int wave = threadIdx.x >> 6;
    const int wt = blockIdx.x * 4 + wave;       // wave tile id, 0..12499
    const size_t nb0 = (size_t)wt * 16;         // first node of this tile

    const float sc_iou = sc_iou_p[0];
    const float sc_c = sc_c_p[0];

    const int ch = lane >> 5;
    const int seg = lane & 31;
    const int rg = lane >> 4;        // C/D row group
    const int col16 = lane & 15;     // C/D col within 16-block
    short* Aw = A[wave];

    // ---------- gather: idx, h rows -> A, h/iou norms (all per-wave) ----------
    const int idxv = child_idx[(size_t)wt * 32 + seg];   // lanes 32-63 duplicate 0-31

    const int k0 = ch * 128 + seg * 4;
    const int sbase = ((k0 >> 5) << 6) + (((k0 >> 3) & 3) << 4);

    float hn_keep = 0.f, in_keep = 0.f;
#pragma unroll 4
    for (int q = 0; q < 16; ++q) {
        const int cix = __shfl(idxv, 2 * q + ch);
        const f32x4 hv = *(const f32x4*)(h_src + (size_t)cix * 128 + seg * 4);
        const int s = sbase + q;
        const int sp = s ^ ((s >> 4) & 7);
        short4v a4;
        a4.x = f2bf(hv.x); a4.y = f2bf(hv.y); a4.z = f2bf(hv.z); a4.w = f2bf(hv.w);
        *(short4v*)&Aw[sp * 8 + (k0 & 7)] = a4;
        const float hss = wsum64(dot4(hv));
        if (lane == q) hn_keep = hss;
    }
#pragma unroll 4
    for (int q = 0; q < 16; ++q) {
        const float* ib = iou + (nb0 + q) * 384;
        const f32x4 v4 = *(const f32x4*)(ib + lane * 4);
        const f32x2 v2 = *(const f32x2*)(ib + 256 + lane * 2);
        const float iss = wsum64(dot4(v4) + v2.x * v2.x + v2.y * v2.y);
        if (lane == q) in_keep = iss;
    }
    asm volatile("s_waitcnt lgkmcnt(0)" ::: "memory");
    __builtin_amdgcn_sched_barrier(0);

    // per-row child indices (rows this lane owns in C/D layout)
    int i0r[4], i1r[4];
#pragma unroll
    for (int e = 0; e < 4; ++e) {
        i0r[e] = __shfl(idxv, (rg * 4 + e) * 2);
        i1r[e] = __shfl(idxv, (rg * 4 + e) * 2 + 1);
    }

    // ---------- pass F0: cols 0..127 (f gate child0), b_f folded ----------
    f32x4 fa[8];
    f32x4 csr[8];
#pragma unroll
    for (int jj = 0; jj < 8; ++jj) {
        const float bv = b_f[jj * 16 + col16];
        fa[jj] = (f32x4){bv, bv, bv, bv};
    }
    gpass<8>(Aw, Blin, lane, rg, 0, fa);

    float c0n2r[4] = {0.f, 0.f, 0.f, 0.f};
#pragma unroll
    for (int jj = 0; jj < 8; ++jj)
#pragma unroll
        for (int e = 0; e < 4; ++e) {
            const float c0 = c_src[(size_t)i0r[e] * 128 + jj * 16 + col16];
            c0n2r[e] += c0 * c0;
            csr[jj][e] = sigm(fa[jj][e]) * c0;
        }

    // ---------- pass F1: cols 128..255 (f gate child1) ----------
#pragma unroll
    for (int jj = 0; jj < 8; ++jj) {
        const float bv = b_f[128 + jj * 16 + col16];
        fa[jj] = (f32x4){bv, bv, bv, bv};
    }
    gpass<8>(Aw, Blin, lane, rg, 8, fa);

    float csn2r[4] = {0.f, 0.f, 0.f, 0.f};
#pragma unroll
    for (int jj = 0; jj < 8; ++jj)
#pragma unroll
        for (int e = 0; e < 4; ++e) {
            const float c1 = c_src[(size_t)i1r[e] * 128 + jj * 16 + col16];
            const float v = csr[jj][e] + sigm(fa[jj][e]) * c1;
            csr[jj][e] = v;
            csn2r[e] += v * v;
        }

    // ---------- norms -> per-row scalars; scale csr in place ----------
    float s_r[4];
#pragma unroll
    for (int e = 0; e < 4; ++e) {
        const float c0n2 = wsum16(c0n2r[e]);
        const float csn2 = wsum16(csn2r[e]);
        const float rs = sc_c * sqrtf(c0n2) / fmaxf(sqrtf(csn2), EPSN);
#pragma unroll
        for (int jj = 0; jj < 8; ++jj) csr[jj][e] *= rs;
        const int row = rg * 4 + e;
        const float hn = __shfl(hn_keep, row);
        const float inn = __shfl(in_keep, row);
        s_r[e] = sc_iou * sqrtf(inn) / fmaxf(sqrtf(hn), EPSN);
    }

    // ---------- IOU in two 4-col-block halves: u -> i (write c) -> o (write h) ----
#pragma unroll
    for (int hh = 0; hh < 2; ++hh) {
        f32x4 ua[4];
#pragma unroll
        for (int jj = 0; jj < 4; ++jj) ua[jj] = (f32x4){0.f, 0.f, 0.f, 0.f};
        gpass<4>(Aw, Blin, lane, rg, 32 + hh * 4, ua);     // u: cols 512..639
#pragma unroll
        for (int jj = 0; jj < 4; ++jj) {
            const int h = (hh * 4 + jj) * 16 + col16;
            const float bu = b_iou[256 + h];
#pragma unroll
            for (int e = 0; e < 4; ++e)
                ua[jj][e] = tanh_fast(ua[jj][e] * s_r[e] + bu);
        }

        f32x4 ia[4];
#pragma unroll
        for (int jj = 0; jj < 4; ++jj) ia[jj] = (f32x4){0.f, 0.f, 0.f, 0.f};
        gpass<4>(Aw, Blin, lane, rg, 16 + hh * 4, ia);     // i: cols 256..383
#pragma unroll
        for (int jj = 0; jj < 4; ++jj) {
            const int h = (hh * 4 + jj) * 16 + col16;
            const float bi = b_iou[h];
#pragma unroll
            for (int e = 0; e < 4; ++e) {
                const float cval = sigm(ia[jj][e] * s_r[e] + bi) * ua[jj][e]
                                 + csr[hh * 4 + jj][e];
                out[(nb0 + rg * 4 + e) * 256 + 128 + h] = cval;
                ua[jj][e] = tanh_fast(cval);               // reuse as tanh(c)
            }
        }

        f32x4 oa[4];
#pragma unroll
        for (int jj = 0; jj < 4; ++jj) oa[jj] = (f32x4){0.f, 0.f, 0.f, 0.f};
        gpass<4>(Aw, Blin, lane, rg, 24 + hh * 4, oa);     // o: cols 384..511
#pragma unroll
        for (int jj = 0; jj < 4; ++jj) {
            const int h = (hh * 4 + jj) * 16 + col16;
            const float bo = b_iou[128 + h];
#pragma unroll
            for (int e = 0; e < 4; ++e)
                out[(nb0 + rg * 4 + e) * 256 + h] =
                    sigm(oa[jj][e] * s_r[e] + bo) * ua[jj][e];
        }
    }
}

extern "C" void kernel_launch(void* const* d_in, const int* in_sizes, int n_in,
                              void* d_out, int out_size, void* d_ws, size_t ws_size,
                              hipStream_t stream) {
    const float* h_src = (const float*)d_in[0];
    const float* c_src = (const float*)d_in[1];
    const float* iou = (const float*)d_in[2];
    const int* cidx = (const int*)d_in[3];
    const float* W_f = (const float*)d_in[4];
    const float* b_f = (const float*)d_in[5];
    const float* W_iou = (const float*)d_in[6];
    const float* b_iou = (const float*)d_in[7];
    const float* s_iou = (const float*)d_in[8];
    const float* s_c = (const float*)d_in[9];
    float* out = (float*)d_out;
    short* Blin = (short*)d_ws;

    const int N = in_sizes[3] / 2;        // 200000
    const int wtiles = N / 16;            // 12500
    const int blocks = wtiles / 4;        // 3125
    hipLaunchKernelGGL(prep_B, dim3(80), dim3(256), 0, stream, W_f, W_iou, Blin);
    hipLaunchKernelGGL(tree_fused, dim3(blocks), dim3(256), 0, stream,
                       h_src, c_src, iou, cidx, b_f, b_iou, s_iou, s_c, Blin, out);
}

// Round 8
// 312.547 us; speedup vs baseline: 5.1528x; 2.4006x over previous
//
#include <hip/hip_runtime.h>
#include <math.h>

typedef __attribute__((ext_vector_type(4))) float f32x4;
typedef __attribute__((ext_vector_type(8))) short bf16x8;
typedef __attribute__((ext_vector_type(4))) short short4v;

#define EPSN 1e-12f
#define TN 16
#define YS 648   // Y row stride in shorts (1296 B): rows offset by 4 banks

__device__ inline short f2bf(float x) {
    union { float f; unsigned u; } v; v.f = x;
    unsigned r = v.u + 0x7fffu + ((v.u >> 16) & 1u);
    return (short)(r >> 16);
}
__device__ inline float bf2f(short s) {
    union { unsigned u; float f; } v;
    v.u = ((unsigned)(unsigned short)s) << 16;
    return v.f;
}
__device__ inline float wsum16(float v) {
    v += __shfl_xor(v, 1);
    v += __shfl_xor(v, 2);
    v += __shfl_xor(v, 4);
    v += __shfl_xor(v, 8);
    return v;
}
__device__ inline float wsum32(float v) {
    v += __shfl_xor(v, 1);
    v += __shfl_xor(v, 2);
    v += __shfl_xor(v, 4);
    v += __shfl_xor(v, 8);
    v += __shfl_xor(v, 16);
    return v;
}
__device__ inline float sigm(float x) { return 1.0f / (1.0f + __expf(-x)); }
__device__ inline float tanh_fast(float x) {
    float a = fabsf(x);
    float e = __expf(2.0f * a);
    float t = 1.0f - 2.0f / (e + 1.0f);
    return copysignf(t, x);
}
__device__ inline float dot4(f32x4 v) { return v.x*v.x + v.y*v.y + v.z*v.z + v.w*v.w; }

// ---- prep: W_f (256x256) + W_iou (384x256) -> bf16 fragment-linear B ----
__global__ void prep_B(const float* __restrict__ W_f, const float* __restrict__ W_iou,
                       short* __restrict__ Blin) {
    int t = blockIdx.x * 256 + threadIdx.x;
    if (t >= 8 * 40 * 64) return;
    int lane = t & 63;
    int jb = (t >> 6) % 40;
    int kb = (t >> 6) / 40;
    int j = jb * 16 + (lane & 15);
    int k = kb * 32 + ((lane >> 4) << 3);
    const float* src = (j < 256) ? (W_f + (size_t)j * 256 + k)
                                 : (W_iou + (size_t)(j - 256) * 256 + k);
    bf16x8 v;
#pragma unroll
    for (int e = 0; e < 8; ++e) v[e] = f2bf(src[e]);
    *(bf16x8*)(Blin + (size_t)t * 8) = v;
}

// GEMM pass over the shared A tile (16x256, fragment-linear XOR layout; r7-verified
// conflict-free): NJJ output col-blocks starting at jbase.
template<int NJJ>
__device__ inline void gpass(const short* __restrict__ A, const short* __restrict__ Blin,
                             int lane, int jbase, f32x4* acc) {
#pragma unroll
    for (int kb = 0; kb < 8; ++kb) {
        const int slot = (kb << 6) + ((lane >> 4) << 4) + (lane & 15);
        const bf16x8 af = *(const bf16x8*)&A[(slot ^ ((slot >> 4) & 7)) << 3];
#pragma unroll
        for (int jj = 0; jj < NJJ; ++jj) {
            const bf16x8 bfr = *(const bf16x8*)(Blin +
                ((size_t)((kb * 40 + jbase + jj) * 64 + lane)) * 8);
            acc[jj] = __builtin_amdgcn_mfma_f32_16x16x32_bf16(af, bfr, acc[jj], 0, 0, 0);
        }
    }
}

// ---- fused: TN=16 tile, 512 threads, all global latency in phase 1 ----
__global__ __launch_bounds__(512, 8) void tree_fused(
    const float* __restrict__ h_src, const float* __restrict__ c_src,
    const float* __restrict__ iou, const int* __restrict__ child_idx,
    const float* __restrict__ b_f, const float* __restrict__ b_iou,
    const float* __restrict__ sc_iou_p, const float* __restrict__ sc_c_p,
    const short* __restrict__ Blin, float* __restrict__ out) {
    __shared__ short A[4096];          // 8 KB A tile (16 rows x 256 cols bf16)
    __shared__ short Y[TN * YS];       // 20736 B GEMM output staging
    __shared__ float biou_lds[384];
    __shared__ float h_n2[TN], iou_n2[TN];

    const int tid = threadIdx.x;
    const int wave = tid >> 6;
    const int lane = tid & 63;
    const size_t nb0 = (size_t)blockIdx.x * TN;

    // epilogue mapping: 32 threads per node, 4 elems each
    const int nd = tid >> 5;
    const int q = tid & 31;
    const int h0 = q * 4;

    const float sc_iou = sc_iou_p[0];
    const float sc_c = sc_c_p[0];

    // ---------- phase 1: ALL global loads ----------
    // iou-norm loads (independent, coalesced): 12 floats/thread
    const float* ibp = iou + (nb0 + nd) * 384 + q * 12;
    const f32x4 u0 = *(const f32x4*)ibp;
    const f32x4 u1 = *(const f32x4*)(ibp + 4);
    const f32x4 u2 = *(const f32x4*)(ibp + 8);

    // indices
    const int2 cc = *(const int2*)(child_idx + (nb0 + nd) * 2);       // epilogue role
    const int nloc = 2 * wave + (lane >> 5);                          // gather role
    const int child = (lane >> 4) & 1;
    const int kin = (lane & 15) * 8;
    const int gidx = child_idx[(nb0 + nloc) * 2 + child];

    // dependent gathers: c rows (held in regs across GEMM) + h rows
    const f32x4 c0v = *(const f32x4*)(c_src + (size_t)cc.x * 128 + h0);
    const f32x4 c1v = *(const f32x4*)(c_src + (size_t)cc.y * 128 + h0);
    const f32x4 hv0 = *(const f32x4*)(h_src + (size_t)gidx * 128 + kin);
    const f32x4 hv1 = *(const f32x4*)(h_src + (size_t)gidx * 128 + kin + 4);

    if (tid < 384) biou_lds[tid] = b_iou[tid];

    // iou norm -> LDS
    float iss = dot4(u0) + dot4(u1) + dot4(u2);
    iss = wsum32(iss);
    if (q == 0) iou_n2[nd] = iss;

    // h_cat norm: per-(node,child) partial over this lane's 8 elems
    float hss = dot4(hv0) + dot4(hv1);
    hss = wsum16(hss);            // per 16-lane group = per (nloc, child)
    hss += __shfl_xor(hss, 16);   // child0 + child1
    if (lane == 0) h_n2[2 * wave] = hss;
    if (lane == 32) h_n2[2 * wave + 1] = hss;

    // A write (fragment-linear + XOR swizzle; 16B/lane, bank-uniform)
    {
        const int kfull = child * 128 + kin;
        const int slot = ((kfull >> 5) << 6) + (((kfull >> 3) & 3) << 4) + nloc;
        bf16x8 a8;
        a8[0] = f2bf(hv0.x); a8[1] = f2bf(hv0.y); a8[2] = f2bf(hv0.z); a8[3] = f2bf(hv0.w);
        a8[4] = f2bf(hv1.x); a8[5] = f2bf(hv1.y); a8[6] = f2bf(hv1.z); a8[7] = f2bf(hv1.w);
        *(bf16x8*)&A[(slot ^ ((slot >> 4) & 7)) << 3] = a8;
    }
    __syncthreads();   // B1

    // ---------- GEMM: Y[16][640] = A * B^T, b_f folded into f-cols ----------
    f32x4 acc[5];
#pragma unroll
    for (int jj = 0; jj < 5; ++jj) {
        const int jb = wave * 5 + jj;
        const float bv = (jb < 16) ? b_f[jb * 16 + (lane & 15)] : 0.0f;
        acc[jj] = (f32x4){bv, bv, bv, bv};
    }
    gpass<5>(A, Blin, lane, wave * 5, acc);

    // Y spill: row=(lane>>4)*4+r, col=jb*16+(lane&15); YS=648 -> 2-way writes (free)
#pragma unroll
    for (int jj = 0; jj < 5; ++jj) {
        const int col = (wave * 5 + jj) * 16 + (lane & 15);
#pragma unroll
        for (int r = 0; r < 4; ++r) {
            const int row = (lane >> 4) * 4 + r;
            Y[row * YS + col] = f2bf(acc[jj][r]);
        }
    }
    __syncthreads();   // B2

    // ---------- epilogue: LDS + regs only ----------
    const short4v yf0 = *(const short4v*)&Y[nd * YS + h0];
    const short4v yf1 = *(const short4v*)&Y[nd * YS + 128 + h0];
    const short4v yi  = *(const short4v*)&Y[nd * YS + 256 + h0];
    const short4v yo  = *(const short4v*)&Y[nd * YS + 384 + h0];
    const short4v yu  = *(const short4v*)&Y[nd * YS + 512 + h0];

    float c0n2 = dot4(c0v);
    c0n2 = wsum32(c0n2);

    float cs[4];
    float csn2 = 0.f;
#pragma unroll
    for (int e = 0; e < 4; ++e) {
        const float f0 = sigm(bf2f(yf0[e]));   // b_f folded into Y
        const float f1 = sigm(bf2f(yf1[e]));
        const float v = f0 * ((const float*)&c0v)[e] + f1 * ((const float*)&c1v)[e];
        cs[e] = v;
        csn2 += v * v;
    }
    csn2 = wsum32(csn2);

    const float s_iou = sc_iou * sqrtf(iou_n2[nd]) / fmaxf(sqrtf(h_n2[nd]), EPSN);
    const float rs = sc_c * sqrtf(c0n2) / fmaxf(sqrtf(csn2), EPSN);

    const f32x4 bi0 = *(const f32x4*)&biou_lds[h0];
    const f32x4 bi1 = *(const f32x4*)&biou_lds[128 + h0];
    const f32x4 bi2 = *(const f32x4*)&biou_lds[256 + h0];

    f32x4 outh, outc;
#pragma unroll
    for (int e = 0; e < 4; ++e) {
        const float iv = bf2f(yi[e]) * s_iou + ((const float*)&bi0)[e];
        const float ov = bf2f(yo[e]) * s_iou + ((const float*)&bi1)[e];
        const float uv = bf2f(yu[e]) * s_iou + ((const float*)&bi2)[e];
        const float cval = sigm(iv) * tanh_fast(uv) + cs[e] * rs;
        const float hval = sigm(ov) * tanh_fast(cval);
        ((float*)&outh)[e] = hval;
        ((float*)&outc)[e] = cval;
    }
    const size_t node = nb0 + nd;
    *(f32x4*)(out + node * 256 + h0) = outh;
    *(f32x4*)(out + node * 256 + 128 + h0) = outc;
}

extern "C" void kernel_launch(void* const* d_in, const int* in_sizes, int n_in,
                              void* d_out, int out_size, void* d_ws, size_t ws_size,
                              hipStream_t stream) {
    const float* h_src = (const float*)d_in[0];
    const float* c_src = (const float*)d_in[1];
    const float* iou = (const float*)d_in[2];
    const int* cidx = (const int*)d_in[3];
    const float* W_f = (const float*)d_in[4];
    const float* b_f = (const float*)d_in[5];
    const float* W_iou = (const float*)d_in[6];
    const float* b_iou = (const float*)d_in[7];
    const float* s_iou = (const float*)d_in[8];
    const float* s_c = (const float*)d_in[9];
    float* out = (float*)d_out;
    short* Blin = (short*)d_ws;

    const int N = in_sizes[3] / 2;        // 200000
    const int ntiles = N / TN;            // 12500
    hipLaunchKernelGGL(prep_B, dim3(80), dim3(256), 0, stream, W_f, W_iou, Blin);
    hipLaunchKernelGGL(tree_fused, dim3(ntiles), dim3(512), 0, stream,
                       h_src, c_src, iou, cidx, b_f, b_iou, s_iou, s_c, Blin, out);
}

// Round 10
// 265.018 us; speedup vs baseline: 6.0769x; 1.1793x over previous
//
#include <hip/hip_runtime.h>
#include <math.h>

typedef __attribute__((ext_vector_type(4))) float f32x4;
typedef __attribute__((ext_vector_type(2))) float f32x2;
typedef __attribute__((ext_vector_type(8))) short bf16x8;
typedef __attribute__((ext_vector_type(4))) short short4v;

#define EPSN 1e-12f
#define TN 32
#define FS 268          // F region row stride (shorts): rg bank-octets disjoint
#define IS 396          // IOU region row stride (shorts)
#define FBASE 8192      // F region base (shorts); A = [0, 8192)
#define UTOT 16768      // max(FBASE + 32*FS, 32*IS) = 16768 shorts = 33536 B

__device__ inline short f2bf(float x) {
    union { float f; unsigned u; } v; v.f = x;
    unsigned r = v.u + 0x7fffu + ((v.u >> 16) & 1u);
    return (short)(r >> 16);
}
__device__ inline float bf2f(short s) {
    union { unsigned u; float f; } v;
    v.u = ((unsigned)(unsigned short)s) << 16;
    return v.f;
}
__device__ inline float wsum64(float v) {
#pragma unroll
    for (int m = 32; m > 0; m >>= 1) v += __shfl_xor(v, m);
    return v;
}
__device__ inline float wsum32(float v) {
    v += __shfl_xor(v, 1);
    v += __shfl_xor(v, 2);
    v += __shfl_xor(v, 4);
    v += __shfl_xor(v, 8);
    v += __shfl_xor(v, 16);
    return v;
}
__device__ inline float sigm(float x) { return 1.0f / (1.0f + __expf(-x)); }
__device__ inline float tanh_fast(float x) {
    float a = fabsf(x);
    float e = __expf(2.0f * a);
    float t = 1.0f - 2.0f / (e + 1.0f);
    return copysignf(t, x);
}
__device__ inline float dot4(f32x4 v) { return v.x*v.x + v.y*v.y + v.z*v.z + v.w*v.w; }

// ---- prep: W_f (256x256) + W_iou (384x256) -> bf16 fragment-linear B ----
__global__ void prep_B(const float* __restrict__ W_f, const float* __restrict__ W_iou,
                       short* __restrict__ Blin) {
    int t = blockIdx.x * 256 + threadIdx.x;
    if (t >= 8 * 40 * 64) return;
    int lane = t & 63;
    int jb = (t >> 6) % 40;
    int kb = (t >> 6) / 40;
    int j = jb * 16 + (lane & 15);
    int k = kb * 32 + ((lane >> 4) << 3);
    const float* src = (j < 256) ? (W_f + (size_t)j * 256 + k)
                                 : (W_iou + (size_t)(j - 256) * 256 + k);
    bf16x8 v;
#pragma unroll
    for (int e = 0; e < 8; ++e) v[e] = f2bf(src[e]);
    *(bf16x8*)(Blin + (size_t)t * 8) = v;
}

// GEMM pass over 32x256 A tile (fragment-linear chunks, XOR-swizzled): NJJ
// col-blocks starting at jbase, 2 M-frags. Fragment index f = kb*128 + kg*32 + row.
template<int NJJ>
__device__ inline void gpass32(const short* __restrict__ A, const short* __restrict__ Blin,
                               int lane, int jbase, f32x4 acc[2][NJJ]) {
    const int la = lane & 15, kg = lane >> 4;
#pragma unroll
    for (int kb = 0; kb < 8; ++kb) {
        bf16x8 af[2];
#pragma unroll
        for (int m = 0; m < 2; ++m) {
            const int f = kb * 128 + kg * 32 + m * 16 + la;
            af[m] = *(const bf16x8*)&A[(f ^ ((f >> 5) & 7)) << 3];
        }
#pragma unroll
        for (int jj = 0; jj < NJJ; ++jj) {
            const bf16x8 b = *(const bf16x8*)(Blin +
                ((size_t)((kb * 40 + jbase + jj) * 64 + lane)) * 8);
            acc[0][jj] = __builtin_amdgcn_mfma_f32_16x16x32_bf16(af[0], b, acc[0][jj], 0, 0, 0);
            acc[1][jj] = __builtin_amdgcn_mfma_f32_16x16x32_bf16(af[1], b, acc[1][jj], 0, 0, 0);
        }
    }
}

// ---- fused: TN=32, N-split GEMM, c-gathers hidden under GEMMs ----
__global__ __launch_bounds__(512, 4) void tree_fused(
    const float* __restrict__ h_src, const float* __restrict__ c_src,
    const float* __restrict__ iou, const int* __restrict__ child_idx,
    const float* __restrict__ b_f, const float* __restrict__ b_iou,
    const float* __restrict__ sc_iou_p, const float* __restrict__ sc_c_p,
    const short* __restrict__ Blin, float* __restrict__ out) {
    __shared__ __align__(16) short U[UTOT];
    __shared__ float h_n2[TN], iou_n2[TN];
    __shared__ int cc_lds[TN][2];

    const int tid = threadIdx.x;
    const int wave = tid >> 6;
    const int lane = tid & 63;
    const int la = lane & 15, kg = lane >> 4;
    const size_t nb0 = (size_t)blockIdx.x * TN;

    const float sc_iou = sc_iou_p[0];
    const float sc_c = sc_c_p[0];

    // hoisted b_f (folded into F accumulators)
    const float bf0 = b_f[(wave * 2 + 0) * 16 + la];
    const float bf1 = b_f[(wave * 2 + 1) * 16 + la];

    // ---------- phase 1: idx -> h gather -> A; h/iou norms; stash idx ----------
    {
        const int child = lane >> 5;
        const int seg = lane & 31;
        int cix[4];
#pragma unroll
        for (int r = 0; r < 4; ++r)
            cix[r] = child_idx[(size_t)(nb0 + wave + 8 * r) * 2 + child];
        f32x4 hv[4];
#pragma unroll
        for (int r = 0; r < 4; ++r)
            hv[r] = *(const f32x4*)(h_src + (size_t)cix[r] * 128 + seg * 4);
#pragma unroll
        for (int r = 0; r < 4; ++r) {
            const int nd = wave + 8 * r;
            const size_t node = nb0 + nd;
            // A write: kfull = child*128 + seg*4 -> kb = child*4 + (seg>>3),
            // kg = (seg>>1)&3, half-chunk (seg&1). f = kb*128 + kg*32 + row.
            const int f = (child * 4 + (seg >> 3)) * 128 + ((seg >> 1) & 3) * 32 + nd;
            const int addr = ((f ^ ((f >> 5) & 7)) << 3) + (seg & 1) * 4;
            short4v a4;
            a4.x = f2bf(hv[r].x); a4.y = f2bf(hv[r].y);
            a4.z = f2bf(hv[r].z); a4.w = f2bf(hv[r].w);
            *(short4v*)&U[addr] = a4;
            if (lane == 0) cc_lds[nd][0] = cix[r];
            if (lane == 32) cc_lds[nd][1] = cix[r];
            float hss = wsum64(dot4(hv[r]));
            const f32x4 v4 = *(const f32x4*)(iou + node * 384 + lane * 4);
            const f32x2 v2 = *(const f32x2*)(iou + node * 384 + 256 + lane * 2);
            float iss = wsum64(dot4(v4) + v2.x * v2.x + v2.y * v2.y);
            if (lane == 0) { h_n2[nd] = hss; iou_n2[nd] = iss; }
        }
    }
    __syncthreads();   // B1: A + cc_lds + norms visible

    // epilogue mapping: 32 threads/node, 4 elems; two 16-node halves
    const int nd0 = tid >> 5;          // 0..15
    const int q = tid & 31;
    const int h0q = q * 4;

    // ---- c prefetch half 0 (flies under both GEMMs) ----
    const int c00 = cc_lds[nd0][0];
    const int c01 = cc_lds[nd0][1];
    const f32x4 c0a = *(const f32x4*)(c_src + (size_t)c00 * 128 + h0q);
    const f32x4 c1a = *(const f32x4*)(c_src + (size_t)c01 * 128 + h0q);

    // ---------- GEMM-F: cols 0..255, b_f folded ----------
    f32x4 accf[2][2];
    accf[0][0] = (f32x4){bf0, bf0, bf0, bf0};
    accf[1][0] = accf[0][0];
    accf[0][1] = (f32x4){bf1, bf1, bf1, bf1};
    accf[1][1] = accf[0][1];
    gpass32<2>(U, Blin, lane, wave * 2, accf);

    // ---- c prefetch half 1 (flies under IOU GEMM) ----
    const int c10 = cc_lds[16 + nd0][0];
    const int c11 = cc_lds[16 + nd0][1];
    const f32x4 c0b = *(const f32x4*)(c_src + (size_t)c10 * 128 + h0q);
    const f32x4 c1b = *(const f32x4*)(c_src + (size_t)c11 * 128 + h0q);

    // F spill
#pragma unroll
    for (int m = 0; m < 2; ++m)
#pragma unroll
        for (int jj = 0; jj < 2; ++jj) {
            const int col = (wave * 2 + jj) * 16 + la;
#pragma unroll
            for (int r = 0; r < 4; ++r) {
                const int row = m * 16 + kg * 4 + r;
                U[FBASE + row * FS + col] = f2bf(accf[m][jj][r]);
            }
        }
    __syncthreads();   // B2: F visible; A intact

    // ---------- GEMM-IOU: cols 256..639 ----------
    f32x4 accio[2][3];
#pragma unroll
    for (int m = 0; m < 2; ++m)
#pragma unroll
        for (int jj = 0; jj < 3; ++jj) accio[m][jj] = (f32x4){0.f, 0.f, 0.f, 0.f};
    gpass32<3>(U, Blin, lane, 16 + wave * 3, accio);

    // ---------- part 1: forget gates + weighted cell sum (two halves) ----------
    float csr[2][4], s_v[2];
#pragma unroll
    for (int p = 0; p < 2; ++p) {
        const int nd = p * 16 + nd0;
        const f32x4 c0v = p ? c0b : c0a;
        const f32x4 c1v = p ? c1b : c1a;
        const short4v yf0 = *(const short4v*)&U[FBASE + nd * FS + h0q];
        const short4v yf1 = *(const short4v*)&U[FBASE + nd * FS + 128 + h0q];
        float c0n2 = wsum32(dot4(c0v));
        float cs[4];
        float csn2 = 0.f;
#pragma unroll
        for (int e = 0; e < 4; ++e) {
            const float f0 = sigm(bf2f(yf0[e]));   // b_f folded into Y
            const float f1 = sigm(bf2f(yf1[e]));
            const float v = f0 * ((const float*)&c0v)[e] + f1 * ((const float*)&c1v)[e];
            cs[e] = v;
            csn2 += v * v;
        }
        csn2 = wsum32(csn2);
        const float rs = sc_c * sqrtf(c0n2) / fmaxf(sqrtf(csn2), EPSN);
#pragma unroll
        for (int e = 0; e < 4; ++e) csr[p][e] = cs[e] * rs;
        s_v[p] = sc_iou * sqrtf(iou_n2[nd]) / fmaxf(sqrtf(h_n2[nd]), EPSN);
    }
    __syncthreads();   // B3: F reads + all A reads done

    // ---------- IOU spill (overlays A + dead F rows) ----------
#pragma unroll
    for (int m = 0; m < 2; ++m)
#pragma unroll
        for (int jj = 0; jj < 3; ++jj) {
            const int col = (wave * 3 + jj) * 16 + la;
#pragma unroll
            for (int r = 0; r < 4; ++r) {
                const int row = m * 16 + kg * 4 + r;
                U[row * IS + col] = f2bf(accio[m][jj][r]);
            }
        }
    __syncthreads();   // B4

    // ---------- part 2: i/o/u gates -> h, c (two halves) ----------
    const f32x4 bi0 = *(const f32x4*)(b_iou + h0q);
    const f32x4 bi1 = *(const f32x4*)(b_iou + 128 + h0q);
    const f32x4 bi2 = *(const f32x4*)(b_iou + 256 + h0q);
#pragma unroll
    for (int p = 0; p < 2; ++p) {
        const int nd = p * 16 + nd0;
        const size_t node = nb0 + nd;
        const short4v yi = *(const short4v*)&U[nd * IS + h0q];
        const short4v yo = *(const short4v*)&U[nd * IS + 128 + h0q];
        const short4v yu = *(const short4v*)&U[nd * IS + 256 + h0q];
        f32x4 outh, outc;
#pragma unroll
        for (int e = 0; e < 4; ++e) {
            const float iv = bf2f(yi[e]) * s_v[p] + ((const float*)&bi0)[e];
            const float ov = bf2f(yo[e]) * s_v[p] + ((const float*)&bi1)[e];
            const float uv = bf2f(yu[e]) * s_v[p] + ((const float*)&bi2)[e];
            const float cval = sigm(iv) * tanh_fast(uv) + csr[p][e];
            const float hval = sigm(ov) * tanh_fast(cval);
            ((float*)&outh)[e] = hval;
            ((float*)&outc)[e] = cval;
        }
        *(f32x4*)(out + node * 256 + h0q) = outh;
        *(f32x4*)(out + node * 256 + 128 + h0q) = outc;
    }
}

extern "C" void kernel_launch(void* const* d_in, const int* in_sizes, int n_in,
                              void* d_out, int out_size, void* d_ws, size_t ws_size,
                              hipStream_t stream) {
    const float* h_src = (const float*)d_in[0];
    const float* c_src = (const float*)d_in[1];
    const float* iou = (const float*)d_in[2];
    const int* cidx = (const int*)d_in[3];
    const float* W_f = (const float*)d_in[4];
    const float* b_f = (const float*)d_in[5];
    const float* W_iou = (const float*)d_in[6];
    const float* b_iou = (const float*)d_in[7];
    const float* s_iou = (const float*)d_in[8];
    const float* s_c = (const float*)d_in[9];
    float* out = (float*)d_out;
    short* Blin = (short*)d_ws;

    const int N = in_sizes[3] / 2;        // 200000
    const int ntiles = N / TN;            // 6250
    hipLaunchKernelGGL(prep_B, dim3(80), dim3(256), 0, stream, W_f, W_iou, Blin);
    hipLaunchKernelGGL(tree_fused, dim3(ntiles), dim3(512), 0, stream,
                       h_src, c_src, iou, cidx, b_f, b_iou, s_iou, s_c, Blin, out);
}